// Round 2
// baseline (1159.444 us; speedup 1.0000x reference)
//
#include <hip/hip_runtime.h>

#define CAPACITY 2000000
#define BATCH 16384

// Phase A: sorted segment_ids -> per-bag start offsets offs[0..BATCH].
// offs[b] = first key index of bag b; offs[BATCH] = n; empty bags collapse.
__global__ void seg_offsets_kernel(const int* __restrict__ seg, int n,
                                   int* __restrict__ offs) {
    int i = blockIdx.x * blockDim.x + threadIdx.x;
    if (i > n) return;
    int cur  = (i < n) ? seg[i]     : BATCH;
    int prev = (i > 0) ? seg[i - 1] : -1;
    for (int s = prev + 1; s <= cur; ++s) offs[s] = i;
}

// Phase B: one 64-lane wave per bag, 2 keys processed per wave-iteration.
// Half-wave h (lanes h*32..h*32+31) reads key k+h's row as float4:
// 32 lanes x 16 B = 512 B = full 128-dim row, fully coalesced.
// Epilogue folds the two half-wave accumulators with shfl_xor(32).
__global__ __launch_bounds__(256) void pool_kernel(
        const int*   __restrict__ keys,
        const float* __restrict__ weight,
        const int*   __restrict__ offs,
        float*       __restrict__ out) {
    int gtid = blockIdx.x * blockDim.x + threadIdx.x;
    int bag  = gtid >> 6;
    if (bag >= BATCH) return;
    int lane = threadIdx.x & 63;
    int half = lane >> 5;     // which key of the pair this lane serves
    int l32  = lane & 31;     // float4 slot within the row

    int s = offs[bag];
    int e = offs[bag + 1];

    const float4* __restrict__ w4 = (const float4*)weight;  // row r at r*32

    float4 acc = make_float4(0.f, 0.f, 0.f, 0.f);

    int k = s;
    // 8 keys per iteration: 4 dwordx4 loads in flight (8 rows outstanding).
    for (; k + 8 <= e; k += 8) {
        float4 v[4];
#pragma unroll
        for (int u = 0; u < 4; ++u) {
            int key = keys[k + 2 * u + half];
            size_t row = (size_t)(key % CAPACITY) + 1;   // row 0 = miss sentinel
            v[u] = w4[(row << 5) + l32];
        }
#pragma unroll
        for (int u = 0; u < 4; ++u) {
            acc.x += v[u].x; acc.y += v[u].y; acc.z += v[u].z; acc.w += v[u].w;
        }
    }
    // tail: pairs
    for (; k + 2 <= e; k += 2) {
        int key = keys[k + half];
        size_t row = (size_t)(key % CAPACITY) + 1;
        float4 v = w4[(row << 5) + l32];
        acc.x += v.x; acc.y += v.y; acc.z += v.z; acc.w += v.w;
    }
    // odd last key: half 0 only
    if (k < e && half == 0) {
        int key = keys[k];
        size_t row = (size_t)(key % CAPACITY) + 1;
        float4 v = w4[(row << 5) + l32];
        acc.x += v.x; acc.y += v.y; acc.z += v.z; acc.w += v.w;
    }

    // fold half-wave partial sums: lane l and lane l^32 hold the same dims
    acc.x += __shfl_xor(acc.x, 32, 64);
    acc.y += __shfl_xor(acc.y, 32, 64);
    acc.z += __shfl_xor(acc.z, 32, 64);
    acc.w += __shfl_xor(acc.w, 32, 64);

    if (half == 0) {
        ((float4*)out)[(size_t)bag * 32 + l32] = acc;
    }
}

extern "C" void kernel_launch(void* const* d_in, const int* in_sizes, int n_in,
                              void* d_out, int out_size, void* d_ws, size_t ws_size,
                              hipStream_t stream) {
    const int*   keys   = (const int*)d_in[0];
    const int*   seg    = (const int*)d_in[1];
    const float* weight = (const float*)d_in[2];
    float*       out    = (float*)d_out;
    int n = in_sizes[0];

    int* offs = (int*)d_ws;  // BATCH+1 ints

    {
        int threads = 256;
        int blocks  = (n + 1 + threads - 1) / threads;
        seg_offsets_kernel<<<blocks, threads, 0, stream>>>(seg, n, offs);
    }
    {
        int threads = 256;                         // 4 bags (waves) per block
        long total  = (long)BATCH * 64;
        int blocks  = (int)((total + threads - 1) / threads);
        pool_kernel<<<blocks, threads, 0, stream>>>(keys, weight, offs, out);
    }
}